// Round 1
// 111.952 us; speedup vs baseline: 1.0470x; 1.0470x over previous
//
#include <hip/hip_runtime.h>
#include <stdint.h>

#define BATCH 8
#define CIN   64
#define DH    32
#define NTOK  4096
#define LOG2E 1.4426950408889634f

typedef float    f4   __attribute__((ext_vector_type(4)));
typedef short    s8v  __attribute__((ext_vector_type(8)));
typedef uint32_t u32;
typedef uint32_t u32x2 __attribute__((ext_vector_type(2)));
typedef uint32_t u32x4 __attribute__((ext_vector_type(4)));

static __device__ __forceinline__ short f2bf(float f) {       // RNE
    union { float f; u32 u; } c; c.f = f;
    u32 u = c.u;
    u32 r = (u + 0x7fffu + ((u >> 16) & 1u)) >> 16;
    return (short)(r & 0xffffu);
}
static __device__ __forceinline__ u32 pk2(float a, float b) { // RNE pack
    return (u32)(uint16_t)f2bf(a) | ((u32)(uint16_t)f2bf(b) << 16);
}
static __device__ __forceinline__ u32 pktr(float a, float b) { // truncate pack (fast)
    union { float f; u32 u; } ca, cb; ca.f = a; cb.f = b;
#if __has_builtin(__builtin_amdgcn_perm)
    return __builtin_amdgcn_perm(cb.u, ca.u, 0x07060302u);
#else
    return (cb.u & 0xffff0000u) | (ca.u >> 16);
#endif
}
static __device__ __forceinline__ float bfhi(u32 u) {
    union { u32 u; float f; } c; c.u = u & 0xffff0000u; return c.f;
}
static __device__ __forceinline__ float bflo(u32 u) {
    union { u32 u; float f; } c; c.u = u << 16; return c.f;
}

// ---------------------------------------------------------------------------
// Kernel 1: MFMA QKV projection.
//   qbf[b][n][32] = bf16((Wq x + bq) * log2e)   (n-major, d contiguous)
//   kbf[b][n][32] = bf16( Wk x + bk )
//   vp  permuted: key n -> cidx=n>>5, p=n&31, qq=(p>>2)&3, j=(p>>4)*4+(p&3);
//                 vp[(((b*128+cidx)*4+qq)*64 + ch)*8 + j]
// V goes through an LDS transpose (vls2) so the global store is coalesced
// dwordx4. Block region = 64 tok x 64 ch = 4096 shorts = 512 u32x4 slots;
// copy-out: 256 threads x 2 slots.
// Block: one batch x 64-token tile. grid (8, 64), 256 threads.
// ---------------------------------------------------------------------------
__global__ __launch_bounds__(256) void proj_kernel(
    const float* __restrict__ h,
    const float* __restrict__ wq, const float* __restrict__ bq,
    const float* __restrict__ wk, const float* __restrict__ bk,
    const float* __restrict__ wv, const float* __restrict__ bv,
    short* __restrict__ qbf, short* __restrict__ kbf, short* __restrict__ vp)
{
    __shared__ short xT [64 * 72];   // [n_local][c] bf16
    __shared__ short wqs[32 * 72];   // [o][c] bf16 (pre-scaled by log2e)
    __shared__ short wks[32 * 72];
    __shared__ short wvs[64 * 72];
    __shared__ short vls2[64 * 68];  // [row=cid2*32+qq*8+j][ch], pad 68
    __shared__ float bqs[32], bks[32], bvs[64];

    const int t   = threadIdx.x;
    const int b   = blockIdx.x;
    const int nt0 = blockIdx.y * 64;

    { // stage x tile: coalesced global reads, bf16 transpose into LDS
        const int c  = t >> 2;
        const int ng = (t & 3) * 16;
        const float* src = h + ((size_t)(b * CIN + c)) * NTOK + nt0 + ng;
        f4 x0 = *(const f4*)(src + 0);
        f4 x1 = *(const f4*)(src + 4);
        f4 x2 = *(const f4*)(src + 8);
        f4 x3 = *(const f4*)(src + 12);
        #pragma unroll
        for (int i = 0; i < 4; ++i) {
            xT[(ng + 0  + i) * 72 + c] = f2bf(x0[i]);
            xT[(ng + 4  + i) * 72 + c] = f2bf(x1[i]);
            xT[(ng + 8  + i) * 72 + c] = f2bf(x2[i]);
            xT[(ng + 12 + i) * 72 + c] = f2bf(x3[i]);
        }
    }
    // vectorized weight staging: f4 loads, packed u32x2 LDS stores
    #pragma unroll
    for (int idx = t; idx < 512; idx += 256) {      // wq/wk: 512 f4 each
        f4 a = *(const f4*)(wq + idx * 4);
        f4 c = *(const f4*)(wk + idx * 4);
        const int o = idx >> 4, cc = (idx & 15) * 4;
        u32x2 qa; qa[0] = pk2(a[0] * LOG2E, a[1] * LOG2E);
                  qa[1] = pk2(a[2] * LOG2E, a[3] * LOG2E);
        u32x2 ka; ka[0] = pk2(c[0], c[1]); ka[1] = pk2(c[2], c[3]);
        *(u32x2*)&wqs[o * 72 + cc] = qa;
        *(u32x2*)&wks[o * 72 + cc] = ka;
    }
    #pragma unroll
    for (int idx = t; idx < 1024; idx += 256) {     // wv: 1024 f4
        f4 a = *(const f4*)(wv + idx * 4);
        const int o = idx >> 4, cc = (idx & 15) * 4;
        u32x2 va; va[0] = pk2(a[0], a[1]); va[1] = pk2(a[2], a[3]);
        *(u32x2*)&wvs[o * 72 + cc] = va;
    }
    if (t < 32) { bqs[t] = bq[t] * LOG2E; bks[t] = bk[t]; }
    if (t < 64) bvs[t] = bv[t];
    __syncthreads();

    const int w    = t >> 6;
    const int ln   = t & 15;
    const int quad = (t >> 4) & 3;
    const int nl   = w * 16 + ln;          // local token (MFMA column)
    const int n    = nt0 + nl;
    const f4 zf4 = {0.f, 0.f, 0.f, 0.f};

    const s8v xb0 = *(const s8v*)&xT[nl * 72 + quad * 8];
    const s8v xb1 = *(const s8v*)&xT[nl * 72 + 32 + quad * 8];

    // ---- q, k (2 o-tiles each) ----
    #pragma unroll
    for (int ot = 0; ot < 2; ++ot) {
        s8v a0 = *(const s8v*)&wqs[(ot * 16 + ln) * 72 + quad * 8];
        s8v a1 = *(const s8v*)&wqs[(ot * 16 + ln) * 72 + 32 + quad * 8];
        f4 d = __builtin_amdgcn_mfma_f32_16x16x32_bf16(a0, xb0, zf4, 0, 0, 0);
        d     = __builtin_amdgcn_mfma_f32_16x16x32_bf16(a1, xb1, d,  0, 0, 0);
        f4 bb = *(const f4*)&bqs[ot * 16 + quad * 4];
        u32x2 pw; pw[0] = pk2(d[0] + bb[0], d[1] + bb[1]);
                  pw[1] = pk2(d[2] + bb[2], d[3] + bb[3]);
        *(u32x2*)(qbf + ((size_t)(b * NTOK + n)) * DH + ot * 16 + quad * 4) = pw;

        s8v c0 = *(const s8v*)&wks[(ot * 16 + ln) * 72 + quad * 8];
        s8v c1 = *(const s8v*)&wks[(ot * 16 + ln) * 72 + 32 + quad * 8];
        f4 e = __builtin_amdgcn_mfma_f32_16x16x32_bf16(c0, xb0, zf4, 0, 0, 0);
        e     = __builtin_amdgcn_mfma_f32_16x16x32_bf16(c1, xb1, e,  0, 0, 0);
        f4 kb = *(const f4*)&bks[ot * 16 + quad * 4];
        u32x2 kw; kw[0] = pk2(e[0] + kb[0], e[1] + kb[1]);
                  kw[1] = pk2(e[2] + kb[2], e[3] + kb[3]);
        *(u32x2*)(kbf + ((size_t)(b * NTOK + n)) * DH + ot * 16 + quad * 4) = kw;
    }

    // ---- v (4 o-tiles) -> packed LDS writes at permuted rows ----
    {
        const int p    = nl & 31;
        const int row  = (nl >> 5) * 32 + ((p >> 2) & 3) * 8   // cid2*32 + qq*8
                       + (p >> 4) * 4 + (p & 3);               // + j
        short* vrow = &vls2[row * 68];
        #pragma unroll
        for (int ot = 0; ot < 4; ++ot) {
            s8v a0 = *(const s8v*)&wvs[(ot * 16 + ln) * 72 + quad * 8];
            s8v a1 = *(const s8v*)&wvs[(ot * 16 + ln) * 72 + 32 + quad * 8];
            f4 d = __builtin_amdgcn_mfma_f32_16x16x32_bf16(a0, xb0, zf4, 0, 0, 0);
            d     = __builtin_amdgcn_mfma_f32_16x16x32_bf16(a1, xb1, d,  0, 0, 0);
            const int ch = ot * 16 + quad * 4;
            u32x2 pw;
            pw[0] = pk2(d[0] + bvs[ch],     d[1] + bvs[ch + 1]);
            pw[1] = pk2(d[2] + bvs[ch + 2], d[3] + bvs[ch + 3]);
            *(u32x2*)&vrow[ch] = pw;
        }
    }
    __syncthreads();

    // ---- coalesced copy-out of the block's contiguous 8 KB vp region ----
    {
        const int g = t >> 5;            // cid2*4 + qq, 0..7
        const int r = t & 31;            // ch pair index
        short tmp[16];
        #pragma unroll
        for (int j = 0; j < 8; ++j)
            #pragma unroll
            for (int cc = 0; cc < 2; ++cc)
                tmp[cc * 8 + j] = vls2[(g * 8 + j) * 68 + r * 2 + cc];
        u32x4* dst = (u32x4*)(vp + ((size_t)(b * 128 + blockIdx.y * 2) * 4) * 64 * 8);
        #pragma unroll
        for (int i = 0; i < 2; ++i)
            dst[t * 2 + i] = ((const u32x4*)tmp)[i];
    }
}

// ---------------------------------------------------------------------------
// Kernel 2: max-free flash attention + Wz projection + residual.
// Block: 256 threads = 4 waves = 4 key-sections, 64 queries.
// grid (8, 64): batch pinned to XCD, 2 blocks/CU.
// Main loop: register-double-buffered K/V prefetch (no barriers in loop, so
// counted-vmcnt pipelining applies) + setprio around the MFMA/exp cluster.
// ---------------------------------------------------------------------------
static __device__ __forceinline__ void load_kv(
    const short* __restrict__ kb2, const s8v* __restrict__ vb2,
    int kt, int ln, int quad,
    s8v& kk0, s8v& kk1, s8v& v0, s8v& v1, s8v& v2, s8v& v3)
{
    const short* kp = kb2 + kt * DH;
    kk0 = *(const s8v*)(kp + ln * DH + quad * 8);
    kk1 = *(const s8v*)(kp + (16 + ln) * DH + quad * 8);
    const s8v* vg = vb2 + (size_t)((kt >> 5) * 4 + quad) * 64 + ln;
    v0 = vg[0]; v1 = vg[16]; v2 = vg[32]; v3 = vg[48];
}

static __device__ __forceinline__ void attn_step(
    const s8v& kk0, const s8v& kk1,
    const s8v& v0, const s8v& v1, const s8v& v2, const s8v& v3,
    const s8v (&qf)[4], const s8v& ones, f4 (&acc)[4][4], f4 (&accl)[4])
{
    const f4 zf4 = {0.f, 0.f, 0.f, 0.f};
    #pragma unroll
    for (int f = 0; f < 4; ++f) {
        f4 sa = __builtin_amdgcn_mfma_f32_16x16x32_bf16(kk0, qf[f], zf4, 0, 0, 0);
        f4 sb = __builtin_amdgcn_mfma_f32_16x16x32_bf16(kk1, qf[f], zf4, 0, 0, 0);
        f4 ea, eb;
        #pragma unroll
        for (int r = 0; r < 4; ++r) {
            ea[r] = __builtin_amdgcn_exp2f(sa[r]);   // scores pre-scaled by log2e
            eb[r] = __builtin_amdgcn_exp2f(sb[r]);
        }
        u32x4 pd;
        pd[0] = pktr(ea[0], ea[1]); pd[1] = pktr(ea[2], ea[3]);
        pd[2] = pktr(eb[0], eb[1]); pd[3] = pktr(eb[2], eb[3]);
        s8v pf = __builtin_bit_cast(s8v, pd);

        accl[f]   = __builtin_amdgcn_mfma_f32_16x16x32_bf16(ones, pf, accl[f],   0, 0, 0);
        acc[f][0] = __builtin_amdgcn_mfma_f32_16x16x32_bf16(v0,   pf, acc[f][0], 0, 0, 0);
        acc[f][1] = __builtin_amdgcn_mfma_f32_16x16x32_bf16(v1,   pf, acc[f][1], 0, 0, 0);
        acc[f][2] = __builtin_amdgcn_mfma_f32_16x16x32_bf16(v2,   pf, acc[f][2], 0, 0, 0);
        acc[f][3] = __builtin_amdgcn_mfma_f32_16x16x32_bf16(v3,   pf, acc[f][3], 0, 0, 0);
    }
}

__global__ __launch_bounds__(256, 2) void attn_kernel(
    const float* __restrict__ h,  const float* __restrict__ wz,
    const float* __restrict__ bz,
    const short* __restrict__ qbf, const short* __restrict__ kbf,
    const short* __restrict__ vp,  float* __restrict__ out)
{
    __shared__ short accb[4][64][72];   // bf16 partial acc slots, 36.9 KB
    __shared__ short zbuf[64][72];      // normalized z [query][ch], 9.2 KB
    __shared__ float lbuf[4][64];       // per-wave partial l, 1 KB

    const int b    = blockIdx.x;
    const int qb0  = blockIdx.y * 64;
    const int tid  = threadIdx.x;
    const int w    = tid >> 6;          // wave = key quarter
    const int lane = tid & 63;
    const int ln   = lane & 15;
    const int quad = lane >> 4;
    const f4 zf4 = {0.f, 0.f, 0.f, 0.f};

    // Q fragments (B-operand): B[d=quad*8+j][n=ln]
    s8v qf[4];
    #pragma unroll
    for (int f = 0; f < 4; ++f)
        qf[f] = *(const s8v*)(qbf + ((size_t)(b * NTOK + qb0 + f * 16 + ln)) * DH + quad * 8);

    f4 acc[4][4];
    f4 accl[4];
    #pragma unroll
    for (int f = 0; f < 4; ++f) {
        accl[f] = zf4;
        #pragma unroll
        for (int ct = 0; ct < 4; ++ct) acc[f][ct] = zf4;
    }
    s8v ones;
    #pragma unroll
    for (int j = 0; j < 8; ++j) ones[j] = (short)0x3F80;   // bf16 1.0

    const short* kb2 = kbf + ((size_t)b * NTOK + w * 1024) * DH;
    const s8v*   vb2 = (const s8v*)(vp + (size_t)b * NTOK * CIN)
                     + (size_t)(w * 32) * 4 * 64;

    // ---- software-pipelined main loop: ping-pong K/V register buffers ----
    s8v kA0, kA1, vA0, vA1, vA2, vA3;
    s8v kB0, kB1, vB0, vB1, vB2, vB3;
    load_kv(kb2, vb2, 0, ln, quad, kA0, kA1, vA0, vA1, vA2, vA3);

    for (int kt = 0; kt < 1024; kt += 64) {
        load_kv(kb2, vb2, kt + 32, ln, quad, kB0, kB1, vB0, vB1, vB2, vB3);
        __builtin_amdgcn_s_setprio(1);
        attn_step(kA0, kA1, vA0, vA1, vA2, vA3, qf, ones, acc, accl);
        __builtin_amdgcn_s_setprio(0);

        if (kt < 960)
            load_kv(kb2, vb2, kt + 64, ln, quad, kA0, kA1, vA0, vA1, vA2, vA3);
        __builtin_amdgcn_s_setprio(1);
        attn_step(kB0, kB1, vB0, vB1, vB2, vB3, qf, ones, acc, accl);
        __builtin_amdgcn_s_setprio(0);
    }

    // ---- write partials (one slot per wave), single combine phase ----
    if (quad == 0) {
        #pragma unroll
        for (int f = 0; f < 4; ++f) lbuf[w][f * 16 + ln] = accl[f][0];
    }
    #pragma unroll
    for (int f = 0; f < 4; ++f) {
        #pragma unroll
        for (int ct = 0; ct < 4; ++ct) {
            u32x2 pw;
            pw[0] = pk2(acc[f][ct][0], acc[f][ct][1]);
            pw[1] = pk2(acc[f][ct][2], acc[f][ct][3]);
            *(u32x2*)&accb[w][f * 16 + ln][ct * 16 + quad * 4] = pw;
        }
    }
    __syncthreads();

    {
        const int q   = tid >> 2;
        const int chg = (tid & 3) * 16;
        float ls = lbuf[0][q] + lbuf[1][q] + lbuf[2][q] + lbuf[3][q];
        float rl = __builtin_amdgcn_rcpf(ls);
        float zv[16];
        #pragma unroll
        for (int i = 0; i < 16; ++i) zv[i] = 0.f;
        #pragma unroll
        for (int w2 = 0; w2 < 4; ++w2) {
            u32x4 ua = *(u32x4*)&accb[w2][q][chg];
            u32x4 ub = *(u32x4*)&accb[w2][q][chg + 8];
            #pragma unroll
            for (int d = 0; d < 4; ++d) {
                zv[d * 2]     += bflo(ua[d]); zv[d * 2 + 1]     += bfhi(ua[d]);
                zv[8 + d * 2] += bflo(ub[d]); zv[8 + d * 2 + 1] += bfhi(ub[d]);
            }
        }
        u32x4 za, zb2;
        #pragma unroll
        for (int d = 0; d < 4; ++d) {
            za[d]  = pk2(zv[d * 2] * rl,     zv[d * 2 + 1] * rl);
            zb2[d] = pk2(zv[8 + d * 2] * rl, zv[8 + d * 2 + 1] * rl);
        }
        *(u32x4*)&zbuf[q][chg]     = za;
        *(u32x4*)&zbuf[q][chg + 8] = zb2;
    }
    __syncthreads();

    // ---- out-projection: wave w handles o-tile w for all 64 queries ----
    {
        const int ot = w;
        s8v wzf[2];
        #pragma unroll
        for (int half = 0; half < 2; ++half) {
            const float* wp = wz + (ot * 16 + ln) * 64 + half * 32 + quad * 8;
            f4 wa = *(const f4*)wp;
            f4 wb = *(const f4*)(wp + 4);
            u32x4 tt;
            tt[0] = pk2(wa[0], wa[1]); tt[1] = pk2(wa[2], wa[3]);
            tt[2] = pk2(wb[0], wb[1]); tt[3] = pk2(wb[2], wb[3]);
            wzf[half] = __builtin_bit_cast(s8v, tt);
        }
        f4 bzv = *(const f4*)(bz + ot * 16 + quad * 4);
        #pragma unroll
        for (int fi = 0; fi < 4; ++fi) {
            const int row = fi * 16 + ln;
            s8v z0 = *(const s8v*)&zbuf[row][quad * 8];
            s8v z1 = *(const s8v*)&zbuf[row][32 + quad * 8];
            f4 oa = __builtin_amdgcn_mfma_f32_16x16x32_bf16(wzf[0], z0, zf4, 0, 0, 0);
            oa     = __builtin_amdgcn_mfma_f32_16x16x32_bf16(wzf[1], z1, oa,  0, 0, 0);
            #pragma unroll
            for (int r = 0; r < 4; ++r) {
                size_t idx = ((size_t)(b * CIN + ot * 16 + quad * 4 + r)) * NTOK
                           + qb0 + row;
                out[idx] = oa[r] + bzv[r] + h[idx];
            }
        }
    }
}

extern "C" void kernel_launch(void* const* d_in, const int* in_sizes, int n_in,
                              void* d_out, int out_size, void* d_ws, size_t ws_size,
                              hipStream_t stream) {
    (void)in_sizes; (void)n_in; (void)out_size; (void)ws_size;
    const float* h  = (const float*)d_in[0];
    const float* wq = (const float*)d_in[1];
    const float* bq = (const float*)d_in[2];
    const float* wk = (const float*)d_in[3];
    const float* bk = (const float*)d_in[4];
    const float* wv = (const float*)d_in[5];
    const float* bv = (const float*)d_in[6];
    const float* wz = (const float*)d_in[7];
    const float* bz = (const float*)d_in[8];
    float* out = (float*)d_out;

    short* qbf = (short*)d_ws;                                // 8*4096*32
    short* kbf = qbf + (size_t)BATCH * NTOK * DH;             // 8*4096*32
    short* vpw = kbf + (size_t)BATCH * NTOK * DH;             // 8*4096*64

    proj_kernel<<<dim3(8, 64), dim3(256), 0, stream>>>(
        h, wq, bq, wk, bk, wv, bv, qbf, kbf, vpw);
    attn_kernel<<<dim3(8, 64), dim3(256), 0, stream>>>(
        h, wz, bz, qbf, kbf, vpw, out);
}

// Round 2
// 109.752 us; speedup vs baseline: 1.0680x; 1.0201x over previous
//
#include <hip/hip_runtime.h>
#include <stdint.h>

#define BATCH 8
#define CIN   64
#define DH    32
#define NTOK  4096
#define LOG2E 1.4426950408889634f

typedef float    f4   __attribute__((ext_vector_type(4)));
typedef short    s8v  __attribute__((ext_vector_type(8)));
typedef uint32_t u32;
typedef uint32_t u32x2 __attribute__((ext_vector_type(2)));
typedef uint32_t u32x4 __attribute__((ext_vector_type(4)));

static __device__ __forceinline__ short f2bf(float f) {       // RNE
    union { float f; u32 u; } c; c.f = f;
    u32 u = c.u;
    u32 r = (u + 0x7fffu + ((u >> 16) & 1u)) >> 16;
    return (short)(r & 0xffffu);
}
static __device__ __forceinline__ u32 pk2(float a, float b) { // RNE pack
    return (u32)(uint16_t)f2bf(a) | ((u32)(uint16_t)f2bf(b) << 16);
}
static __device__ __forceinline__ u32 pktr(float a, float b) { // truncate pack (fast)
    union { float f; u32 u; } ca, cb; ca.f = a; cb.f = b;
#if __has_builtin(__builtin_amdgcn_perm)
    return __builtin_amdgcn_perm(cb.u, ca.u, 0x07060302u);
#else
    return (cb.u & 0xffff0000u) | (ca.u >> 16);
#endif
}
static __device__ __forceinline__ float bfhi(u32 u) {
    union { u32 u; float f; } c; c.u = u & 0xffff0000u; return c.f;
}
static __device__ __forceinline__ float bflo(u32 u) {
    union { u32 u; float f; } c; c.u = u << 16; return c.f;
}

// ---------------------------------------------------------------------------
// Kernel 1: MFMA QKV projection.
//   qbf[b][n][32] = bf16((Wq x + bq) * log2e)   (n-major, d contiguous)
//   kbf[b][n][32] = bf16( Wk x + bk )
//   vp  permuted: key n -> cidx=n>>5, p=n&31, qq=(p>>2)&3, j=(p>>4)*4+(p&3);
//                 vp[(((b*128+cidx)*4+qq)*64 + ch)*8 + j]
// V goes through an LDS transpose (vls2) so the global store is coalesced
// dwordx4. Block region = 64 tok x 64 ch = 4096 shorts = 512 u32x4 slots;
// copy-out: 256 threads x 2 slots.
// Block: one batch x 64-token tile. grid (8, 64), 256 threads.
// ---------------------------------------------------------------------------
__global__ __launch_bounds__(256) void proj_kernel(
    const float* __restrict__ h,
    const float* __restrict__ wq, const float* __restrict__ bq,
    const float* __restrict__ wk, const float* __restrict__ bk,
    const float* __restrict__ wv, const float* __restrict__ bv,
    short* __restrict__ qbf, short* __restrict__ kbf, short* __restrict__ vp)
{
    __shared__ short xT [64 * 72];   // [n_local][c] bf16
    __shared__ short wqs[32 * 72];   // [o][c] bf16 (pre-scaled by log2e)
    __shared__ short wks[32 * 72];
    __shared__ short wvs[64 * 72];
    __shared__ short vls2[64 * 68];  // [row=cid2*32+qq*8+j][ch], pad 68
    __shared__ float bqs[32], bks[32], bvs[64];

    const int t   = threadIdx.x;
    const int b   = blockIdx.x;
    const int nt0 = blockIdx.y * 64;

    { // stage x tile: coalesced global reads, bf16 transpose into LDS
        const int c  = t >> 2;
        const int ng = (t & 3) * 16;
        const float* src = h + ((size_t)(b * CIN + c)) * NTOK + nt0 + ng;
        f4 x0 = *(const f4*)(src + 0);
        f4 x1 = *(const f4*)(src + 4);
        f4 x2 = *(const f4*)(src + 8);
        f4 x3 = *(const f4*)(src + 12);
        #pragma unroll
        for (int i = 0; i < 4; ++i) {
            xT[(ng + 0  + i) * 72 + c] = f2bf(x0[i]);
            xT[(ng + 4  + i) * 72 + c] = f2bf(x1[i]);
            xT[(ng + 8  + i) * 72 + c] = f2bf(x2[i]);
            xT[(ng + 12 + i) * 72 + c] = f2bf(x3[i]);
        }
    }
    // vectorized weight staging: f4 loads, packed u32x2 LDS stores
    #pragma unroll
    for (int idx = t; idx < 512; idx += 256) {      // wq/wk: 512 f4 each
        f4 a = *(const f4*)(wq + idx * 4);
        f4 c = *(const f4*)(wk + idx * 4);
        const int o = idx >> 4, cc = (idx & 15) * 4;
        u32x2 qa; qa[0] = pk2(a[0] * LOG2E, a[1] * LOG2E);
                  qa[1] = pk2(a[2] * LOG2E, a[3] * LOG2E);
        u32x2 ka; ka[0] = pk2(c[0], c[1]); ka[1] = pk2(c[2], c[3]);
        *(u32x2*)&wqs[o * 72 + cc] = qa;
        *(u32x2*)&wks[o * 72 + cc] = ka;
    }
    #pragma unroll
    for (int idx = t; idx < 1024; idx += 256) {     // wv: 1024 f4
        f4 a = *(const f4*)(wv + idx * 4);
        const int o = idx >> 4, cc = (idx & 15) * 4;
        u32x2 va; va[0] = pk2(a[0], a[1]); va[1] = pk2(a[2], a[3]);
        *(u32x2*)&wvs[o * 72 + cc] = va;
    }
    if (t < 32) { bqs[t] = bq[t] * LOG2E; bks[t] = bk[t]; }
    if (t < 64) bvs[t] = bv[t];
    __syncthreads();

    const int w    = t >> 6;
    const int ln   = t & 15;
    const int quad = (t >> 4) & 3;
    const int nl   = w * 16 + ln;          // local token (MFMA column)
    const int n    = nt0 + nl;
    const f4 zf4 = {0.f, 0.f, 0.f, 0.f};

    const s8v xb0 = *(const s8v*)&xT[nl * 72 + quad * 8];
    const s8v xb1 = *(const s8v*)&xT[nl * 72 + 32 + quad * 8];

    // ---- q, k (2 o-tiles each) ----
    #pragma unroll
    for (int ot = 0; ot < 2; ++ot) {
        s8v a0 = *(const s8v*)&wqs[(ot * 16 + ln) * 72 + quad * 8];
        s8v a1 = *(const s8v*)&wqs[(ot * 16 + ln) * 72 + 32 + quad * 8];
        f4 d = __builtin_amdgcn_mfma_f32_16x16x32_bf16(a0, xb0, zf4, 0, 0, 0);
        d     = __builtin_amdgcn_mfma_f32_16x16x32_bf16(a1, xb1, d,  0, 0, 0);
        f4 bb = *(const f4*)&bqs[ot * 16 + quad * 4];
        u32x2 pw; pw[0] = pk2(d[0] + bb[0], d[1] + bb[1]);
                  pw[1] = pk2(d[2] + bb[2], d[3] + bb[3]);
        *(u32x2*)(qbf + ((size_t)(b * NTOK + n)) * DH + ot * 16 + quad * 4) = pw;

        s8v c0 = *(const s8v*)&wks[(ot * 16 + ln) * 72 + quad * 8];
        s8v c1 = *(const s8v*)&wks[(ot * 16 + ln) * 72 + 32 + quad * 8];
        f4 e = __builtin_amdgcn_mfma_f32_16x16x32_bf16(c0, xb0, zf4, 0, 0, 0);
        e     = __builtin_amdgcn_mfma_f32_16x16x32_bf16(c1, xb1, e,  0, 0, 0);
        f4 kb = *(const f4*)&bks[ot * 16 + quad * 4];
        u32x2 kw; kw[0] = pk2(e[0] + kb[0], e[1] + kb[1]);
                  kw[1] = pk2(e[2] + kb[2], e[3] + kb[3]);
        *(u32x2*)(kbf + ((size_t)(b * NTOK + n)) * DH + ot * 16 + quad * 4) = kw;
    }

    // ---- v (4 o-tiles) -> packed LDS writes at permuted rows ----
    {
        const int p    = nl & 31;
        const int row  = (nl >> 5) * 32 + ((p >> 2) & 3) * 8   // cid2*32 + qq*8
                       + (p >> 4) * 4 + (p & 3);               // + j
        short* vrow = &vls2[row * 68];
        #pragma unroll
        for (int ot = 0; ot < 4; ++ot) {
            s8v a0 = *(const s8v*)&wvs[(ot * 16 + ln) * 72 + quad * 8];
            s8v a1 = *(const s8v*)&wvs[(ot * 16 + ln) * 72 + 32 + quad * 8];
            f4 d = __builtin_amdgcn_mfma_f32_16x16x32_bf16(a0, xb0, zf4, 0, 0, 0);
            d     = __builtin_amdgcn_mfma_f32_16x16x32_bf16(a1, xb1, d,  0, 0, 0);
            const int ch = ot * 16 + quad * 4;
            u32x2 pw;
            pw[0] = pk2(d[0] + bvs[ch],     d[1] + bvs[ch + 1]);
            pw[1] = pk2(d[2] + bvs[ch + 2], d[3] + bvs[ch + 3]);
            *(u32x2*)&vrow[ch] = pw;
        }
    }
    __syncthreads();

    // ---- coalesced copy-out of the block's contiguous 8 KB vp region ----
    {
        const int g = t >> 5;            // cid2*4 + qq, 0..7
        const int r = t & 31;            // ch pair index
        short tmp[16];
        #pragma unroll
        for (int j = 0; j < 8; ++j)
            #pragma unroll
            for (int cc = 0; cc < 2; ++cc)
                tmp[cc * 8 + j] = vls2[(g * 8 + j) * 68 + r * 2 + cc];
        u32x4* dst = (u32x4*)(vp + ((size_t)(b * 128 + blockIdx.y * 2) * 4) * 64 * 8);
        #pragma unroll
        for (int i = 0; i < 2; ++i)
            dst[t * 2 + i] = ((const u32x4*)tmp)[i];
    }
}

// ---------------------------------------------------------------------------
// Kernel 2: max-free flash attention + Wz projection + residual.
// Block: 256 threads = 4 waves = 4 key-sections, 64 queries.
// grid (8, 64): batch pinned to XCD, 2 blocks/CU.
// Main loop: register-double-buffered K/V prefetch (distance-1, covers L2
// latency) + setprio around the MFMA/exp cluster. l-sum computed on the
// main VALU pipe (in-lane add tree of the exp values, which are already in
// registers) instead of a `ones` MFMA — frees 4/28 of the MFMA issue and
// the pf->ones dependency; cross-quad reduce happens once after the loop.
// ---------------------------------------------------------------------------
static __device__ __forceinline__ void load_kv(
    const short* __restrict__ kb2, const s8v* __restrict__ vb2,
    int kt, int ln, int quad,
    s8v& kk0, s8v& kk1, s8v& v0, s8v& v1, s8v& v2, s8v& v3)
{
    const short* kp = kb2 + kt * DH;
    kk0 = *(const s8v*)(kp + ln * DH + quad * 8);
    kk1 = *(const s8v*)(kp + (16 + ln) * DH + quad * 8);
    const s8v* vg = vb2 + (size_t)((kt >> 5) * 4 + quad) * 64 + ln;
    v0 = vg[0]; v1 = vg[16]; v2 = vg[32]; v3 = vg[48];
}

static __device__ __forceinline__ void attn_step(
    const s8v& kk0, const s8v& kk1,
    const s8v& v0, const s8v& v1, const s8v& v2, const s8v& v3,
    const s8v (&qf)[4], f4 (&acc)[4][4], float (&lacc)[4])
{
    const f4 zf4 = {0.f, 0.f, 0.f, 0.f};
    #pragma unroll
    for (int f = 0; f < 4; ++f) {
        f4 sa = __builtin_amdgcn_mfma_f32_16x16x32_bf16(kk0, qf[f], zf4, 0, 0, 0);
        f4 sb = __builtin_amdgcn_mfma_f32_16x16x32_bf16(kk1, qf[f], zf4, 0, 0, 0);
        f4 ea, eb;
        #pragma unroll
        for (int r = 0; r < 4; ++r) {
            ea[r] = __builtin_amdgcn_exp2f(sa[r]);   // scores pre-scaled by log2e
            eb[r] = __builtin_amdgcn_exp2f(sb[r]);
        }
        u32x4 pd;
        pd[0] = pktr(ea[0], ea[1]); pd[1] = pktr(ea[2], ea[3]);
        pd[2] = pktr(eb[0], eb[1]); pd[3] = pktr(eb[2], eb[3]);
        s8v pf = __builtin_bit_cast(s8v, pd);

        // in-lane partial row-sum (VALU pipe; lane holds P[keys quad*8+j][q=ln])
        lacc[f] += ((ea[0] + ea[1]) + (ea[2] + ea[3]))
                 + ((eb[0] + eb[1]) + (eb[2] + eb[3]));

        acc[f][0] = __builtin_amdgcn_mfma_f32_16x16x32_bf16(v0, pf, acc[f][0], 0, 0, 0);
        acc[f][1] = __builtin_amdgcn_mfma_f32_16x16x32_bf16(v1, pf, acc[f][1], 0, 0, 0);
        acc[f][2] = __builtin_amdgcn_mfma_f32_16x16x32_bf16(v2, pf, acc[f][2], 0, 0, 0);
        acc[f][3] = __builtin_amdgcn_mfma_f32_16x16x32_bf16(v3, pf, acc[f][3], 0, 0, 0);
    }
}

__global__ __launch_bounds__(256, 2) void attn_kernel(
    const float* __restrict__ h,  const float* __restrict__ wz,
    const float* __restrict__ bz,
    const short* __restrict__ qbf, const short* __restrict__ kbf,
    const short* __restrict__ vp,  float* __restrict__ out)
{
    __shared__ short accb[4][64][72];   // bf16 partial acc slots, 36.9 KB
    __shared__ short zbuf[64][72];      // normalized z [query][ch], 9.2 KB
    __shared__ float lbuf[4][64];       // per-wave partial l, 1 KB

    const int b    = blockIdx.x;
    const int qb0  = blockIdx.y * 64;
    const int tid  = threadIdx.x;
    const int w    = tid >> 6;          // wave = key quarter
    const int lane = tid & 63;
    const int ln   = lane & 15;
    const int quad = lane >> 4;
    const f4 zf4 = {0.f, 0.f, 0.f, 0.f};

    // Q fragments (B-operand): B[d=quad*8+j][n=ln]
    s8v qf[4];
    #pragma unroll
    for (int f = 0; f < 4; ++f)
        qf[f] = *(const s8v*)(qbf + ((size_t)(b * NTOK + qb0 + f * 16 + ln)) * DH + quad * 8);

    f4 acc[4][4];
    float lacc[4];
    #pragma unroll
    for (int f = 0; f < 4; ++f) {
        lacc[f] = 0.f;
        #pragma unroll
        for (int ct = 0; ct < 4; ++ct) acc[f][ct] = zf4;
    }

    const short* kb2 = kbf + ((size_t)b * NTOK + w * 1024) * DH;
    const s8v*   vb2 = (const s8v*)(vp + (size_t)b * NTOK * CIN)
                     + (size_t)(w * 32) * 4 * 64;

    // ---- software-pipelined main loop: ping-pong K/V register buffers ----
    s8v kA0, kA1, vA0, vA1, vA2, vA3;
    s8v kB0, kB1, vB0, vB1, vB2, vB3;
    load_kv(kb2, vb2, 0, ln, quad, kA0, kA1, vA0, vA1, vA2, vA3);

    for (int kt = 0; kt < 1024; kt += 64) {
        load_kv(kb2, vb2, kt + 32, ln, quad, kB0, kB1, vB0, vB1, vB2, vB3);
        __builtin_amdgcn_s_setprio(1);
        attn_step(kA0, kA1, vA0, vA1, vA2, vA3, qf, acc, lacc);
        __builtin_amdgcn_s_setprio(0);

        if (kt < 960)
            load_kv(kb2, vb2, kt + 64, ln, quad, kA0, kA1, vA0, vA1, vA2, vA3);
        __builtin_amdgcn_s_setprio(1);
        attn_step(kB0, kB1, vB0, vB1, vB2, vB3, qf, acc, lacc);
        __builtin_amdgcn_s_setprio(0);
    }

    // ---- cross-quad reduce of l partials, write per-wave slot ----
    #pragma unroll
    for (int f = 0; f < 4; ++f) {
        float l = lacc[f];
        l += __shfl_xor(l, 16);
        l += __shfl_xor(l, 32);
        if (quad == 0) lbuf[w][f * 16 + ln] = l;
    }
    // ---- write acc partials (one slot per wave), single combine phase ----
    #pragma unroll
    for (int f = 0; f < 4; ++f) {
        #pragma unroll
        for (int ct = 0; ct < 4; ++ct) {
            u32x2 pw;
            pw[0] = pk2(acc[f][ct][0], acc[f][ct][1]);
            pw[1] = pk2(acc[f][ct][2], acc[f][ct][3]);
            *(u32x2*)&accb[w][f * 16 + ln][ct * 16 + quad * 4] = pw;
        }
    }
    __syncthreads();

    {
        const int q   = tid >> 2;
        const int chg = (tid & 3) * 16;
        float ls = lbuf[0][q] + lbuf[1][q] + lbuf[2][q] + lbuf[3][q];
        float rl = __builtin_amdgcn_rcpf(ls);
        float zv[16];
        #pragma unroll
        for (int i = 0; i < 16; ++i) zv[i] = 0.f;
        #pragma unroll
        for (int w2 = 0; w2 < 4; ++w2) {
            u32x4 ua = *(u32x4*)&accb[w2][q][chg];
            u32x4 ub = *(u32x4*)&accb[w2][q][chg + 8];
            #pragma unroll
            for (int d = 0; d < 4; ++d) {
                zv[d * 2]     += bflo(ua[d]); zv[d * 2 + 1]     += bfhi(ua[d]);
                zv[8 + d * 2] += bflo(ub[d]); zv[8 + d * 2 + 1] += bfhi(ub[d]);
            }
        }
        u32x4 za, zb2;
        #pragma unroll
        for (int d = 0; d < 4; ++d) {
            za[d]  = pk2(zv[d * 2] * rl,     zv[d * 2 + 1] * rl);
            zb2[d] = pk2(zv[8 + d * 2] * rl, zv[8 + d * 2 + 1] * rl);
        }
        *(u32x4*)&zbuf[q][chg]     = za;
        *(u32x4*)&zbuf[q][chg + 8] = zb2;
    }
    __syncthreads();

    // ---- out-projection: wave w handles o-tile w for all 64 queries ----
    {
        const int ot = w;
        s8v wzf[2];
        #pragma unroll
        for (int half = 0; half < 2; ++half) {
            const float* wp = wz + (ot * 16 + ln) * 64 + half * 32 + quad * 8;
            f4 wa = *(const f4*)wp;
            f4 wb = *(const f4*)(wp + 4);
            u32x4 tt;
            tt[0] = pk2(wa[0], wa[1]); tt[1] = pk2(wa[2], wa[3]);
            tt[2] = pk2(wb[0], wb[1]); tt[3] = pk2(wb[2], wb[3]);
            wzf[half] = __builtin_bit_cast(s8v, tt);
        }
        f4 bzv = *(const f4*)(bz + ot * 16 + quad * 4);
        #pragma unroll
        for (int fi = 0; fi < 4; ++fi) {
            const int row = fi * 16 + ln;
            s8v z0 = *(const s8v*)&zbuf[row][quad * 8];
            s8v z1 = *(const s8v*)&zbuf[row][32 + quad * 8];
            f4 oa = __builtin_amdgcn_mfma_f32_16x16x32_bf16(wzf[0], z0, zf4, 0, 0, 0);
            oa     = __builtin_amdgcn_mfma_f32_16x16x32_bf16(wzf[1], z1, oa,  0, 0, 0);
            #pragma unroll
            for (int r = 0; r < 4; ++r) {
                size_t idx = ((size_t)(b * CIN + ot * 16 + quad * 4 + r)) * NTOK
                           + qb0 + row;
                out[idx] = oa[r] + bzv[r] + h[idx];
            }
        }
    }
}

extern "C" void kernel_launch(void* const* d_in, const int* in_sizes, int n_in,
                              void* d_out, int out_size, void* d_ws, size_t ws_size,
                              hipStream_t stream) {
    (void)in_sizes; (void)n_in; (void)out_size; (void)ws_size;
    const float* h  = (const float*)d_in[0];
    const float* wq = (const float*)d_in[1];
    const float* bq = (const float*)d_in[2];
    const float* wk = (const float*)d_in[3];
    const float* bk = (const float*)d_in[4];
    const float* wv = (const float*)d_in[5];
    const float* bv = (const float*)d_in[6];
    const float* wz = (const float*)d_in[7];
    const float* bz = (const float*)d_in[8];
    float* out = (float*)d_out;

    short* qbf = (short*)d_ws;                                // 8*4096*32
    short* kbf = qbf + (size_t)BATCH * NTOK * DH;             // 8*4096*32
    short* vpw = kbf + (size_t)BATCH * NTOK * DH;             // 8*4096*64

    proj_kernel<<<dim3(8, 64), dim3(256), 0, stream>>>(
        h, wq, bq, wk, bk, wv, bv, qbf, kbf, vpw);
    attn_kernel<<<dim3(8, 64), dim3(256), 0, stream>>>(
        h, wz, bz, qbf, kbf, vpw, out);
}

// Round 3
// 109.153 us; speedup vs baseline: 1.0738x; 1.0055x over previous
//
#include <hip/hip_runtime.h>
#include <stdint.h>

#define BATCH 8
#define CIN   64
#define DH    32
#define NTOK  4096
#define LOG2E 1.4426950408889634f

typedef float    f4   __attribute__((ext_vector_type(4)));
typedef short    s8v  __attribute__((ext_vector_type(8)));
typedef uint32_t u32;
typedef uint32_t u32x2 __attribute__((ext_vector_type(2)));
typedef uint32_t u32x4 __attribute__((ext_vector_type(4)));

// one-instruction RNE pack: lo=bf16(a), hi=bf16(b)  (v_cvt_pk_bf16_f32, gfx950)
static __device__ __forceinline__ u32 pk2(float a, float b) {
    u32 r;
    asm("v_cvt_pk_bf16_f32 %0, %1, %2" : "=v"(r) : "v"(a), "v"(b));
    return r;
}
static __device__ __forceinline__ u32 pktr(float a, float b) { // truncate pack (fast)
    union { float f; u32 u; } ca, cb; ca.f = a; cb.f = b;
#if __has_builtin(__builtin_amdgcn_perm)
    return __builtin_amdgcn_perm(cb.u, ca.u, 0x07060302u);
#else
    return (cb.u & 0xffff0000u) | (ca.u >> 16);
#endif
}
static __device__ __forceinline__ float bfhi(u32 u) {
    union { u32 u; float f; } c; c.u = u & 0xffff0000u; return c.f;
}
static __device__ __forceinline__ float bflo(u32 u) {
    union { u32 u; float f; } c; c.u = u << 16; return c.f;
}

// ---------------------------------------------------------------------------
// Kernel 1: MFMA QKV projection.
//   qbf[b][n][32] = bf16((Wq x + bq) * log2e)   (n-major, d contiguous)
//   kbf[b][n][32] = bf16( Wk x + bk )
//   vp  permuted: key n -> cidx=n>>5, p=n&31, qq=(p>>2)&3, j=(p>>4)*4+(p&3);
//                 vp[(((b*128+cidx)*4+qq)*64 + ch)*8 + j]
// All bf16 packing via v_cvt_pk_bf16_f32 (1 instr / pair).
// x staging: 2 adjacent channels x 8 tokens per thread -> 8 ds_write_b32
// (channel-pair packed) instead of 16 ds_write_b16: half the LDS writes and
// half the conflict cycles at identical layout.
// Block: one batch x 64-token tile. grid (8, 64), 256 threads.
// ---------------------------------------------------------------------------
__global__ __launch_bounds__(256) void proj_kernel(
    const float* __restrict__ h,
    const float* __restrict__ wq, const float* __restrict__ bq,
    const float* __restrict__ wk, const float* __restrict__ bk,
    const float* __restrict__ wv, const float* __restrict__ bv,
    short* __restrict__ qbf, short* __restrict__ kbf, short* __restrict__ vp)
{
    __shared__ short xT [64 * 72];   // [n_local][c] bf16
    __shared__ short wqs[32 * 72];   // [o][c] bf16 (pre-scaled by log2e)
    __shared__ short wks[32 * 72];
    __shared__ short wvs[64 * 72];
    __shared__ short vls2[64 * 68];  // [row=cid2*32+qq*8+j][ch], pad 68
    __shared__ float bqs[32], bks[32], bvs[64];

    const int t   = threadIdx.x;
    const int b   = blockIdx.x;
    const int nt0 = blockIdx.y * 64;

    { // stage x tile: 2 adjacent channels x 8 tokens/thread, packed u32 writes
        const int cp = t >> 3;           // channel pair 0..31 -> c = 2cp, 2cp+1
        const int ng = (t & 7) * 8;      // token group
        const float* s0 = h + ((size_t)(b * CIN + 2 * cp)) * NTOK + nt0 + ng;
        const float* s1 = s0 + NTOK;
        f4 a0 = *(const f4*)(s0 + 0);
        f4 a1 = *(const f4*)(s0 + 4);
        f4 b0 = *(const f4*)(s1 + 0);
        f4 b1 = *(const f4*)(s1 + 4);
        #pragma unroll
        for (int i = 0; i < 4; ++i) {
            *(u32*)&xT[(ng + i)     * 72 + 2 * cp] = pk2(a0[i], b0[i]);
            *(u32*)&xT[(ng + 4 + i) * 72 + 2 * cp] = pk2(a1[i], b1[i]);
        }
    }
    // vectorized weight staging: f4 loads, packed u32x2 LDS stores
    #pragma unroll
    for (int idx = t; idx < 512; idx += 256) {      // wq/wk: 512 f4 each
        f4 a = *(const f4*)(wq + idx * 4);
        f4 c = *(const f4*)(wk + idx * 4);
        const int o = idx >> 4, cc = (idx & 15) * 4;
        u32x2 qa; qa[0] = pk2(a[0] * LOG2E, a[1] * LOG2E);
                  qa[1] = pk2(a[2] * LOG2E, a[3] * LOG2E);
        u32x2 ka; ka[0] = pk2(c[0], c[1]); ka[1] = pk2(c[2], c[3]);
        *(u32x2*)&wqs[o * 72 + cc] = qa;
        *(u32x2*)&wks[o * 72 + cc] = ka;
    }
    #pragma unroll
    for (int idx = t; idx < 1024; idx += 256) {     // wv: 1024 f4
        f4 a = *(const f4*)(wv + idx * 4);
        const int o = idx >> 4, cc = (idx & 15) * 4;
        u32x2 va; va[0] = pk2(a[0], a[1]); va[1] = pk2(a[2], a[3]);
        *(u32x2*)&wvs[o * 72 + cc] = va;
    }
    if (t < 32) { bqs[t] = bq[t] * LOG2E; bks[t] = bk[t]; }
    if (t < 64) bvs[t] = bv[t];
    __syncthreads();

    const int w    = t >> 6;
    const int ln   = t & 15;
    const int quad = (t >> 4) & 3;
    const int nl   = w * 16 + ln;          // local token (MFMA column)
    const int n    = nt0 + nl;
    const f4 zf4 = {0.f, 0.f, 0.f, 0.f};

    const s8v xb0 = *(const s8v*)&xT[nl * 72 + quad * 8];
    const s8v xb1 = *(const s8v*)&xT[nl * 72 + 32 + quad * 8];

    // ---- q, k (2 o-tiles each) ----
    #pragma unroll
    for (int ot = 0; ot < 2; ++ot) {
        s8v a0 = *(const s8v*)&wqs[(ot * 16 + ln) * 72 + quad * 8];
        s8v a1 = *(const s8v*)&wqs[(ot * 16 + ln) * 72 + 32 + quad * 8];
        f4 d = __builtin_amdgcn_mfma_f32_16x16x32_bf16(a0, xb0, zf4, 0, 0, 0);
        d     = __builtin_amdgcn_mfma_f32_16x16x32_bf16(a1, xb1, d,  0, 0, 0);
        f4 bb = *(const f4*)&bqs[ot * 16 + quad * 4];
        u32x2 pw; pw[0] = pk2(d[0] + bb[0], d[1] + bb[1]);
                  pw[1] = pk2(d[2] + bb[2], d[3] + bb[3]);
        *(u32x2*)(qbf + ((size_t)(b * NTOK + n)) * DH + ot * 16 + quad * 4) = pw;

        s8v c0 = *(const s8v*)&wks[(ot * 16 + ln) * 72 + quad * 8];
        s8v c1 = *(const s8v*)&wks[(ot * 16 + ln) * 72 + 32 + quad * 8];
        f4 e = __builtin_amdgcn_mfma_f32_16x16x32_bf16(c0, xb0, zf4, 0, 0, 0);
        e     = __builtin_amdgcn_mfma_f32_16x16x32_bf16(c1, xb1, e,  0, 0, 0);
        f4 kb = *(const f4*)&bks[ot * 16 + quad * 4];
        u32x2 kw; kw[0] = pk2(e[0] + kb[0], e[1] + kb[1]);
                  kw[1] = pk2(e[2] + kb[2], e[3] + kb[3]);
        *(u32x2*)(kbf + ((size_t)(b * NTOK + n)) * DH + ot * 16 + quad * 4) = kw;
    }

    // ---- v (4 o-tiles) -> packed LDS writes at permuted rows ----
    {
        const int p    = nl & 31;
        const int row  = (nl >> 5) * 32 + ((p >> 2) & 3) * 8   // cid2*32 + qq*8
                       + (p >> 4) * 4 + (p & 3);               // + j
        short* vrow = &vls2[row * 68];
        #pragma unroll
        for (int ot = 0; ot < 4; ++ot) {
            s8v a0 = *(const s8v*)&wvs[(ot * 16 + ln) * 72 + quad * 8];
            s8v a1 = *(const s8v*)&wvs[(ot * 16 + ln) * 72 + 32 + quad * 8];
            f4 d = __builtin_amdgcn_mfma_f32_16x16x32_bf16(a0, xb0, zf4, 0, 0, 0);
            d     = __builtin_amdgcn_mfma_f32_16x16x32_bf16(a1, xb1, d,  0, 0, 0);
            const int ch = ot * 16 + quad * 4;
            u32x2 pw;
            pw[0] = pk2(d[0] + bvs[ch],     d[1] + bvs[ch + 1]);
            pw[1] = pk2(d[2] + bvs[ch + 2], d[3] + bvs[ch + 3]);
            *(u32x2*)&vrow[ch] = pw;
        }
    }
    __syncthreads();

    // ---- coalesced copy-out of the block's contiguous 8 KB vp region ----
    {
        const int g = t >> 5;            // cid2*4 + qq, 0..7
        const int r = t & 31;            // ch pair index
        short tmp[16];
        #pragma unroll
        for (int j = 0; j < 8; ++j)
            #pragma unroll
            for (int cc = 0; cc < 2; ++cc)
                tmp[cc * 8 + j] = vls2[(g * 8 + j) * 68 + r * 2 + cc];
        u32x4* dst = (u32x4*)(vp + ((size_t)(b * 128 + blockIdx.y * 2) * 4) * 64 * 8);
        #pragma unroll
        for (int i = 0; i < 2; ++i)
            dst[t * 2 + i] = ((const u32x4*)tmp)[i];
    }
}

// ---------------------------------------------------------------------------
// Kernel 2: max-free flash attention + Wz projection + residual.
// Block: 256 threads = 4 waves = 4 key-sections, 64 queries.
// grid (8, 64): batch pinned to XCD, 2 blocks/CU.
// Main loop: register-double-buffered K/V prefetch (distance-1, covers L2
// latency) + setprio around the MFMA/exp cluster. l-sum on the VALU pipe
// (in-lane add tree), cross-quad reduce after the loop. All epilogue bf16
// packing via v_cvt_pk_bf16_f32.
// ---------------------------------------------------------------------------
static __device__ __forceinline__ void load_kv(
    const short* __restrict__ kb2, const s8v* __restrict__ vb2,
    int kt, int ln, int quad,
    s8v& kk0, s8v& kk1, s8v& v0, s8v& v1, s8v& v2, s8v& v3)
{
    const short* kp = kb2 + kt * DH;
    kk0 = *(const s8v*)(kp + ln * DH + quad * 8);
    kk1 = *(const s8v*)(kp + (16 + ln) * DH + quad * 8);
    const s8v* vg = vb2 + (size_t)((kt >> 5) * 4 + quad) * 64 + ln;
    v0 = vg[0]; v1 = vg[16]; v2 = vg[32]; v3 = vg[48];
}

static __device__ __forceinline__ void attn_step(
    const s8v& kk0, const s8v& kk1,
    const s8v& v0, const s8v& v1, const s8v& v2, const s8v& v3,
    const s8v (&qf)[4], f4 (&acc)[4][4], float (&lacc)[4])
{
    const f4 zf4 = {0.f, 0.f, 0.f, 0.f};
    #pragma unroll
    for (int f = 0; f < 4; ++f) {
        f4 sa = __builtin_amdgcn_mfma_f32_16x16x32_bf16(kk0, qf[f], zf4, 0, 0, 0);
        f4 sb = __builtin_amdgcn_mfma_f32_16x16x32_bf16(kk1, qf[f], zf4, 0, 0, 0);
        f4 ea, eb;
        #pragma unroll
        for (int r = 0; r < 4; ++r) {
            ea[r] = __builtin_amdgcn_exp2f(sa[r]);   // scores pre-scaled by log2e
            eb[r] = __builtin_amdgcn_exp2f(sb[r]);
        }
        u32x4 pd;
        pd[0] = pktr(ea[0], ea[1]); pd[1] = pktr(ea[2], ea[3]);
        pd[2] = pktr(eb[0], eb[1]); pd[3] = pktr(eb[2], eb[3]);
        s8v pf = __builtin_bit_cast(s8v, pd);

        // in-lane partial row-sum (VALU pipe; lane holds P[keys quad*8+j][q=ln])
        lacc[f] += ((ea[0] + ea[1]) + (ea[2] + ea[3]))
                 + ((eb[0] + eb[1]) + (eb[2] + eb[3]));

        acc[f][0] = __builtin_amdgcn_mfma_f32_16x16x32_bf16(v0, pf, acc[f][0], 0, 0, 0);
        acc[f][1] = __builtin_amdgcn_mfma_f32_16x16x32_bf16(v1, pf, acc[f][1], 0, 0, 0);
        acc[f][2] = __builtin_amdgcn_mfma_f32_16x16x32_bf16(v2, pf, acc[f][2], 0, 0, 0);
        acc[f][3] = __builtin_amdgcn_mfma_f32_16x16x32_bf16(v3, pf, acc[f][3], 0, 0, 0);
    }
}

__global__ __launch_bounds__(256, 2) void attn_kernel(
    const float* __restrict__ h,  const float* __restrict__ wz,
    const float* __restrict__ bz,
    const short* __restrict__ qbf, const short* __restrict__ kbf,
    const short* __restrict__ vp,  float* __restrict__ out)
{
    __shared__ short accb[4][64][72];   // bf16 partial acc slots, 36.9 KB
    __shared__ short zbuf[64][72];      // normalized z [query][ch], 9.2 KB
    __shared__ float lbuf[4][64];       // per-wave partial l, 1 KB

    const int b    = blockIdx.x;
    const int qb0  = blockIdx.y * 64;
    const int tid  = threadIdx.x;
    const int w    = tid >> 6;          // wave = key quarter
    const int lane = tid & 63;
    const int ln   = lane & 15;
    const int quad = lane >> 4;
    const f4 zf4 = {0.f, 0.f, 0.f, 0.f};

    // Q fragments (B-operand): B[d=quad*8+j][n=ln]
    s8v qf[4];
    #pragma unroll
    for (int f = 0; f < 4; ++f)
        qf[f] = *(const s8v*)(qbf + ((size_t)(b * NTOK + qb0 + f * 16 + ln)) * DH + quad * 8);

    f4 acc[4][4];
    float lacc[4];
    #pragma unroll
    for (int f = 0; f < 4; ++f) {
        lacc[f] = 0.f;
        #pragma unroll
        for (int ct = 0; ct < 4; ++ct) acc[f][ct] = zf4;
    }

    const short* kb2 = kbf + ((size_t)b * NTOK + w * 1024) * DH;
    const s8v*   vb2 = (const s8v*)(vp + (size_t)b * NTOK * CIN)
                     + (size_t)(w * 32) * 4 * 64;

    // ---- software-pipelined main loop: ping-pong K/V register buffers ----
    s8v kA0, kA1, vA0, vA1, vA2, vA3;
    s8v kB0, kB1, vB0, vB1, vB2, vB3;
    load_kv(kb2, vb2, 0, ln, quad, kA0, kA1, vA0, vA1, vA2, vA3);

    for (int kt = 0; kt < 1024; kt += 64) {
        load_kv(kb2, vb2, kt + 32, ln, quad, kB0, kB1, vB0, vB1, vB2, vB3);
        __builtin_amdgcn_s_setprio(1);
        attn_step(kA0, kA1, vA0, vA1, vA2, vA3, qf, acc, lacc);
        __builtin_amdgcn_s_setprio(0);

        if (kt < 960)
            load_kv(kb2, vb2, kt + 64, ln, quad, kA0, kA1, vA0, vA1, vA2, vA3);
        __builtin_amdgcn_s_setprio(1);
        attn_step(kB0, kB1, vB0, vB1, vB2, vB3, qf, acc, lacc);
        __builtin_amdgcn_s_setprio(0);
    }

    // ---- cross-quad reduce of l partials, write per-wave slot ----
    #pragma unroll
    for (int f = 0; f < 4; ++f) {
        float l = lacc[f];
        l += __shfl_xor(l, 16);
        l += __shfl_xor(l, 32);
        if (quad == 0) lbuf[w][f * 16 + ln] = l;
    }
    // ---- write acc partials (one slot per wave), single combine phase ----
    #pragma unroll
    for (int f = 0; f < 4; ++f) {
        #pragma unroll
        for (int ct = 0; ct < 4; ++ct) {
            u32x2 pw;
            pw[0] = pk2(acc[f][ct][0], acc[f][ct][1]);
            pw[1] = pk2(acc[f][ct][2], acc[f][ct][3]);
            *(u32x2*)&accb[w][f * 16 + ln][ct * 16 + quad * 4] = pw;
        }
    }
    __syncthreads();

    {
        const int q   = tid >> 2;
        const int chg = (tid & 3) * 16;
        float ls = lbuf[0][q] + lbuf[1][q] + lbuf[2][q] + lbuf[3][q];
        float rl = __builtin_amdgcn_rcpf(ls);
        float zv[16];
        #pragma unroll
        for (int i = 0; i < 16; ++i) zv[i] = 0.f;
        #pragma unroll
        for (int w2 = 0; w2 < 4; ++w2) {
            u32x4 ua = *(u32x4*)&accb[w2][q][chg];
            u32x4 ub = *(u32x4*)&accb[w2][q][chg + 8];
            #pragma unroll
            for (int d = 0; d < 4; ++d) {
                zv[d * 2]     += bflo(ua[d]); zv[d * 2 + 1]     += bfhi(ua[d]);
                zv[8 + d * 2] += bflo(ub[d]); zv[8 + d * 2 + 1] += bfhi(ub[d]);
            }
        }
        u32x4 za, zb2;
        #pragma unroll
        for (int d = 0; d < 4; ++d) {
            za[d]  = pk2(zv[d * 2] * rl,     zv[d * 2 + 1] * rl);
            zb2[d] = pk2(zv[8 + d * 2] * rl, zv[8 + d * 2 + 1] * rl);
        }
        *(u32x4*)&zbuf[q][chg]     = za;
        *(u32x4*)&zbuf[q][chg + 8] = zb2;
    }
    __syncthreads();

    // ---- out-projection: wave w handles o-tile w for all 64 queries ----
    {
        const int ot = w;
        s8v wzf[2];
        #pragma unroll
        for (int half = 0; half < 2; ++half) {
            const float* wp = wz + (ot * 16 + ln) * 64 + half * 32 + quad * 8;
            f4 wa = *(const f4*)wp;
            f4 wb = *(const f4*)(wp + 4);
            u32x4 tt;
            tt[0] = pk2(wa[0], wa[1]); tt[1] = pk2(wa[2], wa[3]);
            tt[2] = pk2(wb[0], wb[1]); tt[3] = pk2(wb[2], wb[3]);
            wzf[half] = __builtin_bit_cast(s8v, tt);
        }
        f4 bzv = *(const f4*)(bz + ot * 16 + quad * 4);
        #pragma unroll
        for (int fi = 0; fi < 4; ++fi) {
            const int row = fi * 16 + ln;
            s8v z0 = *(const s8v*)&zbuf[row][quad * 8];
            s8v z1 = *(const s8v*)&zbuf[row][32 + quad * 8];
            f4 oa = __builtin_amdgcn_mfma_f32_16x16x32_bf16(wzf[0], z0, zf4, 0, 0, 0);
            oa     = __builtin_amdgcn_mfma_f32_16x16x32_bf16(wzf[1], z1, oa,  0, 0, 0);
            #pragma unroll
            for (int r = 0; r < 4; ++r) {
                size_t idx = ((size_t)(b * CIN + ot * 16 + quad * 4 + r)) * NTOK
                           + qb0 + row;
                out[idx] = oa[r] + bzv[r] + h[idx];
            }
        }
    }
}

extern "C" void kernel_launch(void* const* d_in, const int* in_sizes, int n_in,
                              void* d_out, int out_size, void* d_ws, size_t ws_size,
                              hipStream_t stream) {
    (void)in_sizes; (void)n_in; (void)out_size; (void)ws_size;
    const float* h  = (const float*)d_in[0];
    const float* wq = (const float*)d_in[1];
    const float* bq = (const float*)d_in[2];
    const float* wk = (const float*)d_in[3];
    const float* bk = (const float*)d_in[4];
    const float* wv = (const float*)d_in[5];
    const float* bv = (const float*)d_in[6];
    const float* wz = (const float*)d_in[7];
    const float* bz = (const float*)d_in[8];
    float* out = (float*)d_out;

    short* qbf = (short*)d_ws;                                // 8*4096*32
    short* kbf = qbf + (size_t)BATCH * NTOK * DH;             // 8*4096*32
    short* vpw = kbf + (size_t)BATCH * NTOK * DH;             // 8*4096*64

    proj_kernel<<<dim3(8, 64), dim3(256), 0, stream>>>(
        h, wq, bq, wk, bk, wv, bv, qbf, kbf, vpw);
    attn_kernel<<<dim3(8, 64), dim3(256), 0, stream>>>(
        h, wz, bz, qbf, kbf, vpw, out);
}